// Round 11
// baseline (474.314 us; speedup 1.0000x reference)
//
#include <hip/hip_runtime.h>

// SSIM loss, round-20: V-first DPP design + FUSED single-launch finalize.
//
// Round-10 post-mortem: DS-pipe theory CONFIRMED. DPP h-chains took the
// main kernel 155 -> 93 us, VALUBusy 34 -> 70%, spill dead (WRITE 120 B,
// VGPR 128). Total 180 us vs main 93 us: the ~87 us gap (2nd launch +
// finalize + inter-dispatch serialization) is now the LARGER bucket, and
// the compute body is near its structural VALU floor (~330 instr/row,
// further cuts <=7% at spill risk). Fix: last-block-ticket fused
// finalize — zero changes to the verified compute body:
//  - each block agent-release-stores its slot, __threadfence(), then
//    device-scope atomicAdd on a 4-byte ticket (memset to 0 per launch);
//  - ticket NBLK-1 block acquire-loads all slots (fences + agent-scope
//    atomics handle cross-XCD L2 non-coherence), reduces in fixed order
//    (bitwise deterministic), writes out[0]. ~3 us tail on one CU.
//  - ws_size guard: falls back to the proven two-kernel path if the
//    workspace lacks slots+ticket bytes.
// Predicted: total 180 -> ~150-170 us (if unchanged, gap!=launch and
// round 12 targets the 30% VALU idle); main kernel 93 -> 94-98 us;
// WRITE ~31 KB; VALUBusy/FETCH/VGPR unchanged; absmax 0.

#define WSZ    11
#define RAD    5
#define IMGN   48
#define IMGH   512
#define IMGW   512
#define OUTC   54               // valid output cols per 64-lane band
#define NBAND  10               // ceil(512/54)
#define NSTRIP 8
#define STRIPR 64               // output rows per strip
#define NBLK   (IMGN * NBAND * NSTRIP)   // 3840

// DPP wave shifts (full-wave, VALU pipe, 0-fill at wave edge).
// FROM_L1: lane t <- lane t-1 (WF_SHL1 0x130); FROM_R1: lane t <- t+1.
#define FROM_L1(x) __int_as_float(__builtin_amdgcn_update_dpp(          \
        0, __float_as_int(x), 0x130, 0xf, 0xf, true))
#define FROM_R1(x) __int_as_float(__builtin_amdgcn_update_dpp(          \
        0, __float_as_int(x), 0x138, 0xf, 0xf, true))

// One symmetric h-tap pair at distance k: shift all 4 fields one more
// lane outward in both directions, accumulate with weight WW.
#define HSTEP(WW)                                                       \
    l0_ = FROM_L1(l0_); l1_ = FROM_L1(l1_);                             \
    l2_ = FROM_L1(l2_); l3_ = FROM_L1(l3_);                             \
    r0_ = FROM_R1(r0_); r1_ = FROM_R1(r1_);                             \
    r2_ = FROM_R1(r2_); r3_ = FROM_R1(r3_);                             \
    h0_ += (WW) * (l0_ + r0_); h1_ += (WW) * (l1_ + r1_);               \
    h2_ += (WW) * (l2_ + r2_); h3_ += (WW) * (l3_ + r3_);

// Load input row (ir) directly into ring slot SLOT (raw, no VALU).
// Row clamped to a legal address; OOB rows are zeroed by e-weights.
#define ISSUE(SLOT, ir)                                                 \
    {                                                                   \
        const int rc_ = min(max((ir), 0), IMGH - 1);                    \
        rp_##SLOT = p[rc_ * IMGW + colc];                               \
        rt_##SLOT = q[rc_ * IMGW + colc];                               \
    }

// Vertical tap: accumulate ring slot SL with (row-masked, SGPR) weight EW.
#define VTAP(SL, EW)                                                    \
    {                                                                   \
        const float pk_ = rp_##SL, tk_ = rt_##SL;                       \
        v0_ += (EW) * pk_;                                              \
        v1_ += (EW) * tk_;                                              \
        v2_ += (EW) * (pk_ * pk_ + tk_ * tk_);                          \
        v3_ += (EW) * (pk_ * tk_);                                      \
    }

// One output row MM: prefetch row MM+10 into slot PF, v-blur rows
// MM-5..MM+5 from ring slots SA..SK, mask edge cols, h-blur via DPP
// shift chains, SSIM accumulate. All slot indices compile-time.
#define OROW(SA,SB,SC,SD,SE,SF,SG,SH,SI,SJ,SK, PF, MM)                  \
    {                                                                   \
        ISSUE(PF, (MM) + 10)                                            \
        const int rr_ = (MM) - RAD;                                     \
        const float e0_  = ((unsigned)(rr_+0)  < (unsigned)IMGH) ? wv0 : 0.f; \
        const float e1_  = ((unsigned)(rr_+1)  < (unsigned)IMGH) ? wv1 : 0.f; \
        const float e2_  = ((unsigned)(rr_+2)  < (unsigned)IMGH) ? wv2 : 0.f; \
        const float e3_  = ((unsigned)(rr_+3)  < (unsigned)IMGH) ? wv3 : 0.f; \
        const float e4_  = ((unsigned)(rr_+4)  < (unsigned)IMGH) ? wv4 : 0.f; \
        const float e5_  = ((unsigned)(rr_+5)  < (unsigned)IMGH) ? wv5 : 0.f; \
        const float e6_  = ((unsigned)(rr_+6)  < (unsigned)IMGH) ? wv4 : 0.f; \
        const float e7_  = ((unsigned)(rr_+7)  < (unsigned)IMGH) ? wv3 : 0.f; \
        const float e8_  = ((unsigned)(rr_+8)  < (unsigned)IMGH) ? wv2 : 0.f; \
        const float e9_  = ((unsigned)(rr_+9)  < (unsigned)IMGH) ? wv1 : 0.f; \
        const float e10_ = ((unsigned)(rr_+10) < (unsigned)IMGH) ? wv0 : 0.f; \
        float v0_ = 0.f, v1_ = 0.f, v2_ = 0.f, v3_ = 0.f;               \
        VTAP(SA, e0_) VTAP(SB, e1_) VTAP(SC, e2_) VTAP(SD, e3_)         \
        VTAP(SE, e4_) VTAP(SF, e5_) VTAP(SG, e6_) VTAP(SH, e7_)         \
        VTAP(SI, e8_) VTAP(SJ, e9_) VTAP(SK, e10_)                      \
        v0_ *= loadm; v1_ *= loadm; v2_ *= loadm; v3_ *= loadm;         \
        float h0_ = wv5 * v0_, h1_ = wv5 * v1_;                         \
        float h2_ = wv5 * v2_, h3_ = wv5 * v3_;                         \
        float l0_ = v0_, l1_ = v1_, l2_ = v2_, l3_ = v3_;               \
        float r0_ = v0_, r1_ = v1_, r2_ = v2_, r3_ = v3_;               \
        HSTEP(wv4) HSTEP(wv3) HSTEP(wv2) HSTEP(wv1) HSTEP(wv0)          \
        const float m1_ = h0_, m2_ = h1_;                               \
        const float m1sq_ = m1_ * m1_, m2sq_ = m2_ * m2_;               \
        const float m12_ = m1_ * m2_;                                   \
        const float vs_ = h2_ - m1sq_ - m2sq_;                          \
        const float cv_ = h3_ - m12_;                                   \
        const float num_ = (2.f * m12_ + 1e-4f) * (2.f * cv_ + 9e-4f);  \
        const float den_ =                                              \
            (m1sq_ + m2sq_ + 1e-4f) * (vs_ + 9e-4f) + 1e-8f;            \
        local += outm * num_ * __builtin_amdgcn_rcpf(den_);             \
    }

// Shared compute body for both kernel variants (FUSED selects finalize).
template <bool FUSED>
__device__ __forceinline__ void ssim_body(
    const float* __restrict__ pred,
    const float* __restrict__ target,
    const float* __restrict__ window,
    double* __restrict__ slots,
    unsigned* counter, float* __restrict__ out, double invN)
{
    const int t = threadIdx.x;

    // Separable 1D window from row sums; symmetric -> 6 unique taps.
    // readlane forces the weights into SGPRs.
    float rsum = 0.f;
    if (t < WSZ) {
        #pragma unroll
        for (int j = 0; j < WSZ; ++j) rsum += window[t * WSZ + j];
    }
    const float wv0 = __int_as_float(
        __builtin_amdgcn_readlane(__float_as_int(rsum), 0));
    const float wv1 = __int_as_float(
        __builtin_amdgcn_readlane(__float_as_int(rsum), 1));
    const float wv2 = __int_as_float(
        __builtin_amdgcn_readlane(__float_as_int(rsum), 2));
    const float wv3 = __int_as_float(
        __builtin_amdgcn_readlane(__float_as_int(rsum), 3));
    const float wv4 = __int_as_float(
        __builtin_amdgcn_readlane(__float_as_int(rsum), 4));
    const float wv5 = __int_as_float(
        __builtin_amdgcn_readlane(__float_as_int(rsum), 5));

    // Block decode: 48 img x 10 bands x 8 strips.
    const int strip = blockIdx.x & (NSTRIP - 1);
    const int rem   = blockIdx.x >> 3;
    const int band  = rem % NBAND;
    const int img   = rem / NBAND;

    // Lane t covers input column band*54 + t - 5 (clamped + masked).
    const int col  = band * OUTC + t - RAD;
    const int colc = min(max(col, 0), IMGW - 1);
    const float loadm = (col >= 0 && col < IMGW) ? 1.f : 0.f;
    // Valid output lanes: 5..58 (full h-neighborhood) and col < 512.
    const float outm =
        (t >= RAD && t < RAD + OUTC && col < IMGW) ? 1.f : 0.f;

    const int base = strip * STRIPR;   // first output row

    const float* __restrict__ p = pred   + (size_t)img * (IMGH * IMGW);
    const float* __restrict__ q = target + (size_t)img * (IMGH * IMGW);

    // RAW register ring: 16 slots x (p,t). Slot of row r = (r-base+5)&15.
    // Rows m+6..m+10 are in flight (loads not yet waited) at output m.
    float rp_0, rp_1, rp_2, rp_3, rp_4, rp_5, rp_6, rp_7,
          rp_8, rp_9, rp_10, rp_11, rp_12, rp_13, rp_14, rp_15;
    float rt_0, rt_1, rt_2, rt_3, rt_4, rt_5, rt_6, rt_7,
          rt_8, rt_9, rt_10, rt_11, rt_12, rt_13, rt_14, rt_15;
    float local = 0.f;

    // Prologue: rows base-5..base+9 into slots 0..14.
    ISSUE(0,  base - 5)
    ISSUE(1,  base - 4)
    ISSUE(2,  base - 3)
    ISSUE(3,  base - 2)
    ISSUE(4,  base - 1)
    ISSUE(5,  base + 0)
    ISSUE(6,  base + 1)
    ISSUE(7,  base + 2)
    ISSUE(8,  base + 3)
    ISSUE(9,  base + 4)
    ISSUE(10, base + 5)
    ISSUE(11, base + 6)
    ISSUE(12, base + 7)
    ISSUE(13, base + 8)
    ISSUE(14, base + 9)

    // Main: 4 x 16 output rows; all slot indices static (period 16).
    #pragma unroll 1
    for (int ub = 0; ub < 4; ++ub) {
        const int mb_ = base + ub * 16;
        OROW(0,1,2,3,4,5,6,7,8,9,10,     15, mb_ + 0)
        OROW(1,2,3,4,5,6,7,8,9,10,11,     0, mb_ + 1)
        OROW(2,3,4,5,6,7,8,9,10,11,12,    1, mb_ + 2)
        OROW(3,4,5,6,7,8,9,10,11,12,13,   2, mb_ + 3)
        OROW(4,5,6,7,8,9,10,11,12,13,14,  3, mb_ + 4)
        OROW(5,6,7,8,9,10,11,12,13,14,15, 4, mb_ + 5)
        OROW(6,7,8,9,10,11,12,13,14,15,0, 5, mb_ + 6)
        OROW(7,8,9,10,11,12,13,14,15,0,1, 6, mb_ + 7)
        OROW(8,9,10,11,12,13,14,15,0,1,2, 7, mb_ + 8)
        OROW(9,10,11,12,13,14,15,0,1,2,3, 8, mb_ + 9)
        OROW(10,11,12,13,14,15,0,1,2,3,4, 9, mb_ + 10)
        OROW(11,12,13,14,15,0,1,2,3,4,5, 10, mb_ + 11)
        OROW(12,13,14,15,0,1,2,3,4,5,6,  11, mb_ + 12)
        OROW(13,14,15,0,1,2,3,4,5,6,7,   12, mb_ + 13)
        OROW(14,15,0,1,2,3,4,5,6,7,8,    13, mb_ + 14)
        OROW(15,0,1,2,3,4,5,6,7,8,9,     14, mb_ + 15)
    }

    // Wave shuffle reduce; lane 0 publishes this block's slot.
    #pragma unroll
    for (int off = 32; off > 0; off >>= 1)
        local += __shfl_down(local, off, 64);

    if (!FUSED) {
        if (t == 0) slots[blockIdx.x] = (double)local;
        return;
    }

    // Fused finalize: last-block ticket. Release slot -> fence -> ticket;
    // winner fences + acquire-loads all slots (cross-XCD safe), reduces
    // in fixed order (deterministic), writes the scalar.
    if (t == 0)
        __hip_atomic_store(&slots[blockIdx.x], (double)local,
                           __ATOMIC_RELEASE, __HIP_MEMORY_SCOPE_AGENT);
    __threadfence();
    int old = 0;
    if (t == 0)
        old = (int)__hip_atomic_fetch_add(counter, 1u, __ATOMIC_ACQ_REL,
                                          __HIP_MEMORY_SCOPE_AGENT);
    old = __shfl(old, 0, 64);
    if (old == NBLK - 1) {
        __threadfence();
        double s = 0.0;
        for (int i = t; i < NBLK; i += 64)
            s += __hip_atomic_load(&slots[i], __ATOMIC_ACQUIRE,
                                   __HIP_MEMORY_SCOPE_AGENT);
        #pragma unroll
        for (int off = 32; off > 0; off >>= 1)
            s += __shfl_down(s, off, 64);
        if (t == 0) out[0] = (float)(1.0 - s * invN);
    }
}

__global__ __launch_bounds__(64, 2) void ssim_fused_kernel(
    const float* __restrict__ pred, const float* __restrict__ target,
    const float* __restrict__ window, double* __restrict__ slots,
    unsigned* counter, float* __restrict__ out, double invN)
{
    ssim_body<true>(pred, target, window, slots, counter, out, invN);
}

__global__ __launch_bounds__(64, 2) void ssim_vreg_kernel(
    const float* __restrict__ pred, const float* __restrict__ target,
    const float* __restrict__ window, double* __restrict__ slots)
{
    ssim_body<false>(pred, target, window, slots, nullptr, nullptr, 0.0);
}

__global__ __launch_bounds__(256) void ssim_finalize_kernel(
    const double* __restrict__ slots, float* __restrict__ out, double invN)
{
    __shared__ double red[4];
    const int t = threadIdx.x;
    double s = 0.0;
    for (int i = t; i < NBLK; i += 256) s += slots[i];
    #pragma unroll
    for (int off = 32; off > 0; off >>= 1)
        s += __shfl_down(s, off, 64);
    const int lane = t & 63, wid = t >> 6;
    if (lane == 0) red[wid] = s;
    __syncthreads();
    if (t == 0)
        out[0] = (float)(1.0 - (red[0] + red[1] + red[2] + red[3]) * invN);
}

extern "C" void kernel_launch(void* const* d_in, const int* in_sizes, int n_in,
                              void* d_out, int out_size, void* d_ws, size_t ws_size,
                              hipStream_t stream)
{
    const float* pred   = (const float*)d_in[0];
    const float* target = (const float*)d_in[1];
    const float* window = (const float*)d_in[2];
    float*  out   = (float*)d_out;
    double* slots = (double*)d_ws;               // NBLK*8 = 30720 B
    const double invN = 1.0 / ((double)IMGN * IMGH * IMGW);

    if (ws_size >= NBLK * sizeof(double) + sizeof(unsigned)) {
        // Fused single-launch path: 4-byte ticket after the slots.
        unsigned* counter =
            (unsigned*)((char*)d_ws + NBLK * sizeof(double));
        hipMemsetAsync(counter, 0, sizeof(unsigned), stream);
        ssim_fused_kernel<<<NBLK, 64, 0, stream>>>(
            pred, target, window, slots, counter, out, invN);
    } else {
        // Fallback: proven two-kernel path (round-18 behavior).
        ssim_vreg_kernel<<<NBLK, 64, 0, stream>>>(
            pred, target, window, slots);
        ssim_finalize_kernel<<<1, 256, 0, stream>>>(slots, out, invN);
    }
}